// Round 10
// baseline (110.504 us; speedup 1.0000x reference)
//
#include <hip/hip_runtime.h>
#include <hip/hip_bf16.h>
#include <stdint.h>

// SimpleVectorQuantizer: vecs [16,32,128,64] f32, codebook [512,64] f32.
// Outputs (flat f32): vecs_hat [65536*64], z [65536] (as float), l_commit, l_codebook.
//
// Round 21: r20's null (4 blocks/CU == 1 block/CU == 101.6us) kills TLP for
// good, and r20 also moved B-conversion out of the scan with zero effect ->
// B-prologue exonerated. The never-yet-ablated block is the A-PROLOGUE
// (f32 loads + 32-deep f64 vsq chain + 64 bf16-split conversions at the
// scan's 2-waves/SIMD). This round splits it out (ablate-by-removal, the
// only method that has produced information): vq_preA runs at full
// occupancy, writes a pre-split bf16 hi/lo fragment image (16MB; layout =
// exactly the 16B fragments scan lanes need, coalesced 64B segments) plus
// the exact-f64 vsq table (FMA order and shuffle tree bit-identical: lane
// = v*4+q, xor 1/2 == old xor 16/32). Scan prologue shrinks to 8x16B loads
// + table reads; scan HBM read halves. Rest of scan = r20 exactly (4-pass
// 32KB LDS image, prebuilt swizzled B, packed-key merge, exact-f64 rescue,
// batched gather). Decision tree: total ~90 -> A-prologue was the cost;
// total ~105 -> K-loop owns it, next round = double-K diagnostic.

#define VQ_K 64
#define VQ_S 512
#define NTHREADS 256                     // 4 waves
#define NWAVES 4
#define MT 2                             // m-tiles per wave -> 32 vectors/wave
#define VPB 128                          // vectors per block
#define NTILES 32                        // 512 codewords / 16 per tile
#define NPASS 4
#define TPP 8                            // tiles per pass
#define PASSB 32768                      // bytes per pass image (8 tiles x 4KB)
#define ROWB 256                         // B row: 64 hi bf16 + 64 lo bf16 (packed)
#define TILEB 4096
#define CSQ_OFF (VQ_S * ROWB)            // 131072
#define FRAG_OFF 0x100000                // frag image at ws+1MB (16MB)
#define VSQ_OFF 0x1100000                // vsq table at ws+17MB (256KB)
#define CELL 7.62939453125e-6f           // f32 ulp at ref-score magnitude ~64
#define GAP_THRESH (8.0f * CELL)

typedef __attribute__((ext_vector_type(8))) short bf16x8;
typedef __attribute__((ext_vector_type(4))) float f32x4;

static __device__ __forceinline__ unsigned short f2bf_rne(float f) {
    unsigned u = __float_as_uint(f);
    unsigned r = (u + 0x7fffu + ((u >> 16) & 1u)) >> 16;
    return (unsigned short)r;
}
static __device__ __forceinline__ float bf2f(unsigned short h) {
    return __uint_as_float(((unsigned)h) << 16);
}
static __device__ __forceinline__ void gload_lds16(const void* g, void* l) {
    __builtin_amdgcn_global_load_lds(
        (const __attribute__((address_space(1))) unsigned int*)g,
        (__attribute__((address_space(3))) unsigned int*)l, 16, 0, 0);
}

// K1: one wave per codebook row. Builds the PRE-SWIZZLED global B image
// + exact csq table. Zeroes loss.
__global__ __launch_bounds__(256, 1) void vq_prep(
    const float* __restrict__ cb, unsigned char* __restrict__ bimg,
    float* __restrict__ out_loss) {
    if (blockIdx.x == 0 && threadIdx.x == 0) { out_loss[0] = 0.f; out_loss[1] = 0.f; }
    const int lane = threadIdx.x & 63;
    const int row = blockIdx.x * 4 + (threadIdx.x >> 6);
    float c = cb[(size_t)row * VQ_K + lane];
    double d = (double)c * (double)c;
#pragma unroll
    for (int off = 1; off <= 32; off <<= 1) d += __shfl_xor(d, off, 64);
    unsigned short hi = f2bf_rne(c);
    unsigned short lo = f2bf_rne(c - bf2f(hi));
    const int t = row >> 4;
    const int r = row & 15;
    const int xr = (r & 7) << 4;
    unsigned char* tb = bimg + (size_t)t * TILEB + r * ROWB;
    *(unsigned short*)(tb + ((2 * lane) ^ xr)) = hi;          // hi: cols [0,128)
    *(unsigned short*)(tb + (128 + ((2 * lane) ^ xr))) = lo;  // lo: cols [128,256)
    if (lane == 0) ((float*)(bimg + CSQ_OFF))[row] = (float)d;
}

// K1b: A-prologue at full occupancy. Thread (v, q=0..3) converts 16 elems
// (chunks q and q+4) of vector v into bf16 hi/lo fragments + exact f64 vsq.
// FMA order and reduction tree bit-identical to the original in-scan code.
__global__ __launch_bounds__(256) void vq_preA(
    const float* __restrict__ vecs, unsigned char* __restrict__ frag,
    float* __restrict__ vsqg) {
    const int g = blockIdx.x * 256 + threadIdx.x;   // 0..262143
    const int v = g >> 2;
    const int q = g & 3;
    const float* vp = vecs + (size_t)v * VQ_K + q * 8;
    float4 a0 = ((const float4*)vp)[0];
    float4 a1 = ((const float4*)vp)[1];
    float4 b0 = ((const float4*)(vp + 32))[0];
    float4 b1 = ((const float4*)(vp + 32))[1];
    float w1[8] = {a0.x, a0.y, a0.z, a0.w, a1.x, a1.y, a1.z, a1.w};
    float w2[8] = {b0.x, b0.y, b0.z, b0.w, b1.x, b1.y, b1.z, b1.w};
    double p = 0.0;
#pragma unroll
    for (int j = 0; j < 8; ++j) {
        double d1 = (double)w1[j], d2 = (double)w2[j];
        p = fma(d1, d1, p); p = fma(d2, d2, p);
    }
    // lane = (v&15)*4 + q: xor1 = q^1 (old q0<->q1 pairing), xor2 = q^2.
    // Tree (p0+p1)+(p2+p3) == original shfl_xor(16) then (32). Bit-exact.
    p += __shfl_xor(p, 1, 64);
    p += __shfl_xor(p, 2, 64);
    bf16x8 h1, h2, l1, l2;
#pragma unroll
    for (int j = 0; j < 8; ++j) {
        unsigned short hh1 = f2bf_rne(w1[j]);
        unsigned short hh2 = f2bf_rne(w2[j]);
        h1[j] = (short)hh1;
        h2[j] = (short)hh2;
        l1[j] = (short)f2bf_rne(w1[j] - bf2f(hh1));
        l2[j] = (short)f2bf_rne(w2[j] - bf2f(hh2));
    }
    unsigned char* base = frag + (size_t)v * 256;
    *(bf16x8*)(base + q * 16) = h1;              // hi elems [0,32)
    *(bf16x8*)(base + 64 + q * 16) = h2;         // hi elems [32,64)
    *(bf16x8*)(base + 128 + q * 16) = l1;        // lo elems [0,32)
    *(bf16x8*)(base + 192 + q * 16) = l2;        // lo elems [32,64)
    if (q == 0) vsqg[v] = (float)p;
}

// K2: 4-pass LDS-resident scan; A comes pre-split from the frag image.
__global__ __launch_bounds__(NTHREADS, 2) void vq_mfma(
    const float* __restrict__ vecs, const float* __restrict__ codebook,
    const unsigned char* __restrict__ bimg, const unsigned char* __restrict__ frag,
    const float* __restrict__ vsqg,
    float* __restrict__ out_hat, float* __restrict__ out_z,
    float* __restrict__ out_loss, float inv_n) {
    __shared__ __align__(16) unsigned char blds[PASSB];   // 32768 B quarter image
    __shared__ float csq_sh[VQ_S];       // exact csq (rescue + mh derivation)
    __shared__ float vsq_all[VPB];
    __shared__ int zsh[VPB];
    __shared__ int rlist[VPB];
    __shared__ int rn;
    __shared__ float loss_sh;

    const int tid = threadIdx.x;
    const int wave = tid >> 6;                    // 0..3
    const int lane = tid & 63;
    const int m = lane & 15;
    const int q = lane >> 4;
    const int blockbase = blockIdx.x * VPB;
    const int wavebase = blockbase + wave * 32;   // 32 vectors per wave

    if (tid == 0) { rn = 0; loss_sh = 0.f; }

    // ---- issue pass-0 image copy FIRST (8x gload_lds, linear, 8-deep MLP) ----
    {
        const unsigned char* g0 = bimg + wave * 1024 + lane * 16;
        unsigned char* l0 = &blds[wave * 1024];
#pragma unroll
        for (int it = 0; it < 8; ++it)
            gload_lds16(g0 + it * 4096, l0 + it * 4096);
    }

    // ---- A fragments: 8 x 16B pre-split loads (coalesced 64B segments) ----
    const unsigned char* fb0 = frag + (size_t)(wavebase + m) * 256 + q * 16;
    const unsigned char* fb1 = frag + (size_t)(wavebase + 16 + m) * 256 + q * 16;
    bf16x8 ah1[MT], ah2[MT], al1[MT], al2[MT];
    ah1[0] = *(const bf16x8*)(fb0);
    ah2[0] = *(const bf16x8*)(fb0 + 64);
    al1[0] = *(const bf16x8*)(fb0 + 128);
    al2[0] = *(const bf16x8*)(fb0 + 192);
    ah1[1] = *(const bf16x8*)(fb1);
    ah2[1] = *(const bf16x8*)(fb1 + 64);
    al1[1] = *(const bf16x8*)(fb1 + 128);
    al2[1] = *(const bf16x8*)(fb1 + 192);

    // csq table: 512 entries, 256 threads -> 2 each.  vsq: 128 entries.
    {
        const float* csqg = (const float*)(bimg + CSQ_OFF);
        csq_sh[tid] = csqg[tid];
        csq_sh[tid + 256] = csqg[tid + 256];
    }
    if (tid < VPB) vsq_all[tid] = vsqg[blockbase + tid];
    __syncthreads();   // implicit vmcnt(0) drain: pass-0 image + tables resident

    // ---- 4-pass K-loop: pure LDS + MFMA + ranking inside each pass ----
    float t1u[8], t2u[8];
    int t1i[8];
#pragma unroll
    for (int st = 0; st < 8; ++st) { t1u[st] = -3.4e38f; t2u[st] = -3.4e38f; t1i[st] = 0; }
    const f32x4 zero4 = {0.f, 0.f, 0.f, 0.f};
    const int xm = (m & 7) << 4;

    for (int p = 0; p < NPASS; ++p) {
#pragma unroll
        for (int tt = 0; tt < TPP; ++tt) {
            const int t = p * TPP + tt;
            const unsigned char* rb = &blds[(tt * 16 + m) * ROWB];
            bf16x8 c1 = *(const bf16x8*)(rb + ((q * 16) ^ xm));
            bf16x8 c2 = *(const bf16x8*)(rb + ((64 + q * 16) ^ xm));
            bf16x8 c3 = *(const bf16x8*)(rb + (128 + ((q * 16) ^ xm)));
            bf16x8 c4 = *(const bf16x8*)(rb + (128 + ((64 + q * 16) ^ xm)));

            const float mh = -0.5f * csq_sh[t * 16 + m];
            const f32x4 ci = {mh, mh, mh, mh};
            const int nidx = t * 16 + m;
#pragma unroll
            for (int mt = 0; mt < MT; ++mt) {
                f32x4 accA = __builtin_amdgcn_mfma_f32_16x16x32_bf16(ah1[mt], c1, zero4, 0, 0, 0);
                f32x4 accB = __builtin_amdgcn_mfma_f32_16x16x32_bf16(ah2[mt], c2, ci, 0, 0, 0);
                accA = __builtin_amdgcn_mfma_f32_16x16x32_bf16(al1[mt], c1, accA, 0, 0, 0);
                accB = __builtin_amdgcn_mfma_f32_16x16x32_bf16(al2[mt], c2, accB, 0, 0, 0);
                accA = __builtin_amdgcn_mfma_f32_16x16x32_bf16(ah1[mt], c3, accA, 0, 0, 0);
                accB = __builtin_amdgcn_mfma_f32_16x16x32_bf16(ah2[mt], c4, accB, 0, 0, 0);
#pragma unroll
                for (int r = 0; r < 4; ++r) {
                    const int st = mt * 4 + r;
                    float u = accA[r] + accB[r];
                    bool gt = u > t1u[st];                          // strict: first index wins
                    t2u[st] = fminf(fmaxf(u, t2u[st]), t1u[st]);    // 2nd-largest
                    t1u[st] = fmaxf(t1u[st], u);
                    t1i[st] = gt ? nidx : t1i[st];
                }
            }
        }
        if (p < NPASS - 1) {
            __syncthreads();                    // all waves done reading this pass
            const unsigned char* gp = bimg + (p + 1) * PASSB + wave * 1024 + lane * 16;
            unsigned char* l0 = &blds[wave * 1024];
#pragma unroll
            for (int it = 0; it < 8; ++it)
                gload_lds16(gp + it * 4096, l0 + it * 4096);
            __syncthreads();                    // implicit vmcnt(0): next image ready
        }
    }

    // ---- convert to score space (sc = -2u) and butterfly-merge 16 columns ----
    float t1s[8], t2s[8];
    unsigned long long pk[8];
#pragma unroll
    for (int st = 0; st < 8; ++st) {
        t1s[st] = -2.0f * t1u[st];
        t2s[st] = -2.0f * t2u[st];
        unsigned u = __float_as_uint(t1s[st]);
        unsigned mono = (u & 0x80000000u) ? ~u : (u | 0x80000000u);
        pk[st] = ((unsigned long long)mono << 32) | (unsigned)t1i[st];
    }
#pragma unroll
    for (int dd = 1; dd <= 8; dd <<= 1) {
#pragma unroll
        for (int st = 0; st < 8; ++st) {
            unsigned long long opk = __shfl_xor(pk[st], dd, 64);
            float o1 = __shfl_xor(t1s[st], dd, 64);
            float o2 = __shfl_xor(t2s[st], dd, 64);
            t2s[st] = fminf(fmaxf(t1s[st], o1), fminf(t2s[st], o2));
            t1s[st] = fminf(t1s[st], o1);
            pk[st] = opk < pk[st] ? opk : pk[st];
        }
    }

    // ---- writers: lanes m<8 own state st=m -> vector wave*32+(m>>2)*16+q*4+(m&3)
    float w1s = 3.4e38f, w2s = 3.4e38f;
    unsigned long long wpk = 0;
#pragma unroll
    for (int i = 0; i < 8; ++i) {
        bool sel = (m == i);
        w1s = sel ? t1s[i] : w1s;
        w2s = sel ? t2s[i] : w2s;
        wpk = sel ? pk[i] : wpk;
    }
    const bool writer = (m < 8);
    const int vloc = wave * 32 + ((m >> 2) & 1) * 16 + q * 4 + (m & 3);
    float dl = 0.f;
    if (writer) {
        zsh[vloc] = (int)(wpk & 0xffffffffull);
        if (w2s - w1s <= GAP_THRESH) {
            int pos = atomicAdd(&rn, 1);
            rlist[pos] = vloc;
        }
        float full = vsq_all[vloc] + w1s;          // loss = relu(vsq + best)
        dl = (full < 0.f ? 0.f : full) * inv_n;
    }
#pragma unroll
    for (int off = 32; off >= 1; off >>= 1) dl += __shfl_down(dl, off, 64);
    if (lane == 0) atomicAdd(&loss_sh, dl);

    __syncthreads();

    // ---- in-block exact rescue: wave w -> rlist[base+w]. qq-outer / j-inner
    // (8 independent f64 chains; per-acc FMA order unchanged -> bit-identical).
    const int nr = rn;
    for (int rbase = 0; rbase < nr; rbase += NWAVES) {
        const int slot = rbase + wave;
        if (slot < nr) {                       // wave-uniform
            const int rv = rlist[slot];
            const float4* vrow4 = (const float4*)(vecs + (size_t)(blockbase + rv) * VQ_K);
            const float vsqr = vsq_all[rv];
            double acc0 = 0.0, acc1 = 0.0, acc2 = 0.0, acc3 = 0.0;
            double acc4 = 0.0, acc5 = 0.0, acc6 = 0.0, acc7 = 0.0;
            const float4* crow = (const float4*)(codebook + (size_t)(lane * 8) * VQ_K);
#pragma unroll
            for (int qq = 0; qq < VQ_K / 4; ++qq) {
                float4 tt = vrow4[qq];         // wave-uniform -> scalar loads
                float4 c0 = crow[qq];
                float4 c1 = crow[16 + qq];
                float4 c2 = crow[32 + qq];
                float4 c3 = crow[48 + qq];
                float4 c4 = crow[64 + qq];
                float4 c5 = crow[80 + qq];
                float4 c6 = crow[96 + qq];
                float4 c7 = crow[112 + qq];
                acc0 = fma((double)c0.x, (double)tt.x, acc0); acc0 = fma((double)c0.y, (double)tt.y, acc0);
                acc0 = fma((double)c0.z, (double)tt.z, acc0); acc0 = fma((double)c0.w, (double)tt.w, acc0);
                acc1 = fma((double)c1.x, (double)tt.x, acc1); acc1 = fma((double)c1.y, (double)tt.y, acc1);
                acc1 = fma((double)c1.z, (double)tt.z, acc1); acc1 = fma((double)c1.w, (double)tt.w, acc1);
                acc2 = fma((double)c2.x, (double)tt.x, acc2); acc2 = fma((double)c2.y, (double)tt.y, acc2);
                acc2 = fma((double)c2.z, (double)tt.z, acc2); acc2 = fma((double)c2.w, (double)tt.w, acc2);
                acc3 = fma((double)c3.x, (double)tt.x, acc3); acc3 = fma((double)c3.y, (double)tt.y, acc3);
                acc3 = fma((double)c3.z, (double)tt.z, acc3); acc3 = fma((double)c3.w, (double)tt.w, acc3);
                acc4 = fma((double)c4.x, (double)tt.x, acc4); acc4 = fma((double)c4.y, (double)tt.y, acc4);
                acc4 = fma((double)c4.z, (double)tt.z, acc4); acc4 = fma((double)c4.w, (double)tt.w, acc4);
                acc5 = fma((double)c5.x, (double)tt.x, acc5); acc5 = fma((double)c5.y, (double)tt.y, acc5);
                acc5 = fma((double)c5.z, (double)tt.z, acc5); acc5 = fma((double)c5.w, (double)tt.w, acc5);
                acc6 = fma((double)c6.x, (double)tt.x, acc6); acc6 = fma((double)c6.y, (double)tt.y, acc6);
                acc6 = fma((double)c6.z, (double)tt.z, acc6); acc6 = fma((double)c6.w, (double)tt.w, acc6);
                acc7 = fma((double)c7.x, (double)tt.x, acc7); acc7 = fma((double)c7.y, (double)tt.y, acc7);
                acc7 = fma((double)c7.z, (double)tt.z, acc7); acc7 = fma((double)c7.w, (double)tt.w, acc7);
            }
            unsigned long long best = ~0ull;
            double accs[8] = {acc0, acc1, acc2, acc3, acc4, acc5, acc6, acc7};
#pragma unroll
            for (int j = 0; j < 8; ++j) {
                const int s = lane * 8 + j;
                float e = (float)accs[j];
                float sc = fmaf(-2.0f, e, vsqr) + csq_sh[s];   // exact ref rounding
                unsigned u = __float_as_uint(sc);
                unsigned mono = (u & 0x80000000u) ? ~u : (u | 0x80000000u);
                unsigned long long pkr = ((unsigned long long)mono << 32) | (unsigned)s;
                best = pkr < best ? pkr : best;
            }
#pragma unroll
            for (int off = 32; off >= 1; off >>= 1) {
                unsigned long long o = __shfl_down(best, off, 64);
                best = o < best ? o : best;
            }
            if (lane == 0) zsh[rv] = (int)(best & 0xffffffffull);
        }
    }
    __syncthreads();

    // ---- loss atomics (2/block), coalesced z write + MLP-batched gather ----
    if (tid == 0) {
        float l = loss_sh;
        atomicAdd(&out_loss[0], l);
        atomicAdd(&out_loss[1], l);
    }
    if (tid < VPB) out_z[blockbase + tid] = (float)zsh[tid];
    {
        const float4* cb4g = (const float4*)codebook;
        float4* hat4 = (float4*)(out_hat + (size_t)blockbase * VQ_K);
        int zz[8];
#pragma unroll
        for (int i = 0; i < 8; ++i) zz[i] = zsh[(tid + i * NTHREADS) >> 4];
        float4 gv[8];
#pragma unroll
        for (int i = 0; i < 8; ++i) {
            const int f = tid + i * NTHREADS;
            gv[i] = cb4g[zz[i] * (VQ_K / 4) + (f & 15)];
        }
#pragma unroll
        for (int i = 0; i < 8; ++i) hat4[tid + i * NTHREADS] = gv[i];
    }
}

extern "C" void kernel_launch(void* const* d_in, const int* in_sizes, int n_in,
                              void* d_out, int out_size, void* d_ws, size_t ws_size,
                              hipStream_t stream) {
    const float* vecs = (const float*)d_in[0];
    const float* codebook = (const float*)d_in[1];
    float* out = (float*)d_out;

    const int nvec = in_sizes[0] / VQ_K;            // 65536
    unsigned char* ws = (unsigned char*)d_ws;
    unsigned char* bimg = ws;                       // 133120 B (image + csq)
    unsigned char* frag = ws + FRAG_OFF;            // 16 MB pre-split A image
    float* vsqg = (float*)(ws + VSQ_OFF);           // 256 KB exact vsq

    float* out_hat = out;
    float* out_z = out + (size_t)nvec * VQ_K;
    float* out_loss = out + out_size - 2;

    vq_prep<<<VQ_S / 4, 256, 0, stream>>>(codebook, bimg, out_loss);
    vq_preA<<<(nvec * 4) / 256, 256, 0, stream>>>(vecs, frag, vsqg);
    vq_mfma<<<nvec / VPB, NTHREADS, 0, stream>>>(
        vecs, codebook, bimg, frag, vsqg, out_hat, out_z, out_loss,
        1.0f / (float)nvec);
}

// Round 11
// 105.518 us; speedup vs baseline: 1.0473x; 1.0473x over previous
//
#include <hip/hip_runtime.h>
#include <hip/hip_bf16.h>
#include <stdint.h>

// SimpleVectorQuantizer: vecs [16,32,128,64] f32, codebook [512,64] f32.
// Outputs (flat f32): vecs_hat [65536*64], z [65536] (as float), l_commit, l_codebook.
//
// Round 22: ablation matrix complete -- B-delivery (4 schemes), occupancy
// (r20: 4 waves/SIMD = +-0.0us), B-conversion (r20), A-prologue (r21),
// gather (r17) ALL null. The 38us K-loop does zero global traffic yet runs
// at CPI~14 nominal: only dependent-op latency fits. The 3-deep chained
// MFMA per accumulator (dependent-MFMA latency never isolated on gfx950)
// + MFMA->VALU ranking dependency is the last testable stall. This round:
//   1) each tile's 6-MFMA 3-chain -> 4 independent streams, max depth 2
//      (p1..p4; +2 f32 adds per element);
//   2) FULL unroll of the 32-tile loop (register renaming decouples tiles;
//      scheduler can overlap tile t ranking with t+1 MFMAs/ds_reads).
// Numerics: regrouped summation shifts scan scores ~1 ulp -- inside the
// 8-CELL rescue band (which exists to absorb scan error); rescue/exact
// path unchanged -> absmax stays 0. Base = r19 (best, 101.6us): 512thr,
// LDS-resident 131KB B image, MLP-batched A loads + gather, packed-key
// merge, exact-f64 in-block rescue.

#define VQ_K 64
#define VQ_S 512
#define NTHREADS 512                     // 8 waves
#define MT 2                             // m-tiles per wave -> 32 vectors/wave
#define VPB 256                          // vectors per block
#define NTILES 32                        // 512 codewords / 16 per tile
#define ROWB 256                         // B row: 64 hi bf16 + 64 lo bf16 (packed)
#define CELL 7.62939453125e-6f           // f32 ulp at ref-score magnitude ~64
#define GAP_THRESH (8.0f * CELL)

typedef __attribute__((ext_vector_type(8))) short bf16x8;
typedef __attribute__((ext_vector_type(4))) float f32x4;

static __device__ __forceinline__ unsigned short f2bf_rne(float f) {
    unsigned u = __float_as_uint(f);
    unsigned r = (u + 0x7fffu + ((u >> 16) & 1u)) >> 16;
    return (unsigned short)r;
}
static __device__ __forceinline__ float bf2f(unsigned short h) {
    return __uint_as_float(((unsigned)h) << 16);
}

// K1: one wave per codebook row; lane k handles element k. csq only + zero loss.
__global__ __launch_bounds__(256, 1) void vq_prep(
    const float* __restrict__ cb, float* __restrict__ csqg,
    float* __restrict__ out_loss) {
    if (blockIdx.x == 0 && threadIdx.x == 0) { out_loss[0] = 0.f; out_loss[1] = 0.f; }
    const int lane = threadIdx.x & 63;
    const int row = blockIdx.x * 4 + (threadIdx.x >> 6);
    float c = cb[(size_t)row * VQ_K + lane];
    double d = (double)c * (double)c;
#pragma unroll
    for (int off = 1; off <= 32; off <<= 1) d += __shfl_xor(d, off, 64);
    if (lane == 0) csqg[row] = (float)d;
}

// K2: all-LDS-resident B image, shallow-chain MFMA scan, full unroll.
__global__ __launch_bounds__(NTHREADS, 1) void vq_mfma(
    const float* __restrict__ vecs, const float* __restrict__ codebook,
    const float* __restrict__ csqg,
    float* __restrict__ out_hat, float* __restrict__ out_z,
    float* __restrict__ out_loss, float inv_n) {
    __shared__ __align__(16) unsigned char blds[VQ_S * ROWB];  // 131072 B
    __shared__ float csq_sh[VQ_S];       // exact csq (rescue)
    __shared__ float csqn2_sh[VQ_S];     // -csq/2 (C-init for the scan)
    __shared__ float vsq_all[VPB];
    __shared__ int zsh[VPB];
    __shared__ int rlist[VPB];
    __shared__ int rn;
    __shared__ float loss_sh;

    const int tid = threadIdx.x;
    const int wave = tid >> 6;                    // 0..7
    const int lane = tid & 63;
    const int m = lane & 15;
    const int q = lane >> 4;
    const int blockbase = blockIdx.x * VPB;
    const int wavebase = blockbase + wave * 32;   // 32 vectors per wave

    if (tid == 0) { rn = 0; loss_sh = 0.f; }

    // ---- ISSUE ALL A LOADS FIRST (8 x float4, max per-wave MLP) ----
    const float* vp0 = vecs + (size_t)(wavebase + m) * VQ_K + q * 8;
    const float* vp1 = vecs + (size_t)(wavebase + 16 + m) * VQ_K + q * 8;
    float4 A0a = ((const float4*)vp0)[0];
    float4 A0b = ((const float4*)vp0)[1];
    float4 A0c = ((const float4*)(vp0 + 32))[0];
    float4 A0d = ((const float4*)(vp0 + 32))[1];
    float4 A1a = ((const float4*)vp1)[0];
    float4 A1b = ((const float4*)vp1)[1];
    float4 A1c = ((const float4*)(vp1 + 32))[0];
    float4 A1d = ((const float4*)(vp1 + 32))[1];

    // csq tables (512 entries, 512 threads).
    {
        float c = csqg[tid];
        csq_sh[tid] = c;
        csqn2_sh[tid] = -0.5f * c;
    }
    // B image build runs while A loads are in flight.
    {
        const int row = tid;
        const float4* crow = (const float4*)(codebook + (size_t)row * VQ_K);
        const int xr = (row & 7) << 4;
        unsigned char* rowp = &blds[row * ROWB];
#pragma unroll
        for (int j = 0; j < 8; ++j) {             // 8 chunks of 8 elems
            float4 f0 = crow[2 * j];
            float4 f1 = crow[2 * j + 1];
            float w[8] = {f0.x, f0.y, f0.z, f0.w, f1.x, f1.y, f1.z, f1.w};
            bf16x8 hi8, lo8;
#pragma unroll
            for (int e = 0; e < 8; ++e) {
                unsigned short h = f2bf_rne(w[e]);
                hi8[e] = (short)h;
                lo8[e] = (short)f2bf_rne(w[e] - bf2f(h));
            }
            *(bf16x8*)(rowp + ((j * 16) ^ xr)) = hi8;          // hi: bytes [0,128)
            *(bf16x8*)(rowp + (128 + ((j * 16) ^ xr))) = lo8;  // lo: bytes [128,256)
        }
    }

    // ---- A fragments (bf16 split) + exact vsq (consume staged loads) ----
    bf16x8 ah1[MT], ah2[MT], al1[MT], al2[MT];
#pragma unroll
    for (int mt = 0; mt < MT; ++mt) {
        float4 a0 = (mt == 0) ? A0a : A1a;
        float4 a1 = (mt == 0) ? A0b : A1b;
        float4 b0 = (mt == 0) ? A0c : A1c;
        float4 b1 = (mt == 0) ? A0d : A1d;
        float w1[8] = {a0.x, a0.y, a0.z, a0.w, a1.x, a1.y, a1.z, a1.w};
        float w2[8] = {b0.x, b0.y, b0.z, b0.w, b1.x, b1.y, b1.z, b1.w};
        double p = 0.0;
#pragma unroll
        for (int j = 0; j < 8; ++j) {
            double d1 = (double)w1[j], d2 = (double)w2[j];
            p = fma(d1, d1, p); p = fma(d2, d2, p);
        }
        p += __shfl_xor(p, 16, 64);
        p += __shfl_xor(p, 32, 64);
        if (q == 0) vsq_all[wave * 32 + mt * 16 + m] = (float)p;
#pragma unroll
        for (int j = 0; j < 8; ++j) {
            unsigned short h1 = f2bf_rne(w1[j]);
            unsigned short h2 = f2bf_rne(w2[j]);
            ah1[mt][j] = (short)h1;
            ah2[mt][j] = (short)h2;
            al1[mt][j] = (short)f2bf_rne(w1[j] - bf2f(h1));
            al2[mt][j] = (short)f2bf_rne(w2[j] - bf2f(h2));
        }
    }
    __syncthreads();   // B image + csq tables + vsq resident

    // ---- K-loop: pure LDS + MFMA + ranking. Full unroll, shallow chains. ----
    float t1u[8], t2u[8];
    int t1i[8];
#pragma unroll
    for (int st = 0; st < 8; ++st) { t1u[st] = -3.4e38f; t2u[st] = -3.4e38f; t1i[st] = 0; }
    const f32x4 zero4 = {0.f, 0.f, 0.f, 0.f};
    const int xm = (m & 7) << 4;

#pragma unroll
    for (int t = 0; t < NTILES; ++t) {
        const unsigned char* rb = &blds[(t * 16 + m) * ROWB];
        bf16x8 c1 = *(const bf16x8*)(rb + ((q * 16) ^ xm));
        bf16x8 c2 = *(const bf16x8*)(rb + ((64 + q * 16) ^ xm));
        bf16x8 c3 = *(const bf16x8*)(rb + (128 + ((q * 16) ^ xm)));
        bf16x8 c4 = *(const bf16x8*)(rb + (128 + ((64 + q * 16) ^ xm)));

        const float mh = csqn2_sh[t * 16 + m];
        const f32x4 ci = {mh, mh, mh, mh};
        const int nidx = t * 16 + m;
#pragma unroll
        for (int mt = 0; mt < MT; ++mt) {
            // 4 independent MFMA streams, max dependency depth 2 (was one
            // 3-deep chain per accumulator): p1,p3 are 2-chains, p2,p4 singles.
            f32x4 p1 = __builtin_amdgcn_mfma_f32_16x16x32_bf16(ah1[mt], c1, ci, 0, 0, 0);
            f32x4 p2 = __builtin_amdgcn_mfma_f32_16x16x32_bf16(ah1[mt], c3, zero4, 0, 0, 0);
            f32x4 p3 = __builtin_amdgcn_mfma_f32_16x16x32_bf16(ah2[mt], c2, zero4, 0, 0, 0);
            f32x4 p4 = __builtin_amdgcn_mfma_f32_16x16x32_bf16(ah2[mt], c4, zero4, 0, 0, 0);
            p1 = __builtin_amdgcn_mfma_f32_16x16x32_bf16(al1[mt], c1, p1, 0, 0, 0);
            p3 = __builtin_amdgcn_mfma_f32_16x16x32_bf16(al2[mt], c2, p3, 0, 0, 0);
#pragma unroll
            for (int r = 0; r < 4; ++r) {
                const int st = mt * 4 + r;
                float u = (p1[r] + p2[r]) + (p3[r] + p4[r]);
                bool gt = u > t1u[st];                          // strict: first index wins
                t2u[st] = fminf(fmaxf(u, t2u[st]), t1u[st]);    // 2nd-largest (med3 idiom)
                t1u[st] = fmaxf(t1u[st], u);
                t1i[st] = gt ? nidx : t1i[st];
            }
        }
    }

    // ---- convert to score space (sc = -2u) and butterfly-merge 16 columns ----
    float t1s[8], t2s[8];
    unsigned long long pk[8];
#pragma unroll
    for (int st = 0; st < 8; ++st) {
        t1s[st] = -2.0f * t1u[st];
        t2s[st] = -2.0f * t2u[st];
        unsigned u = __float_as_uint(t1s[st]);
        unsigned mono = (u & 0x80000000u) ? ~u : (u | 0x80000000u);
        pk[st] = ((unsigned long long)mono << 32) | (unsigned)t1i[st];
    }
#pragma unroll
    for (int dd = 1; dd <= 8; dd <<= 1) {
#pragma unroll
        for (int st = 0; st < 8; ++st) {
            unsigned long long opk = __shfl_xor(pk[st], dd, 64);
            float o1 = __shfl_xor(t1s[st], dd, 64);
            float o2 = __shfl_xor(t2s[st], dd, 64);
            t2s[st] = fminf(fmaxf(t1s[st], o1), fminf(t2s[st], o2));
            t1s[st] = fminf(t1s[st], o1);
            pk[st] = opk < pk[st] ? opk : pk[st];
        }
    }

    // ---- writers: lanes m<8 own state st=m -> vector wave*32+(m>>2)*16+q*4+(m&3)
    float w1s = 3.4e38f, w2s = 3.4e38f;
    unsigned long long wpk = 0;
#pragma unroll
    for (int i = 0; i < 8; ++i) {
        bool sel = (m == i);
        w1s = sel ? t1s[i] : w1s;
        w2s = sel ? t2s[i] : w2s;
        wpk = sel ? pk[i] : wpk;
    }
    const bool writer = (m < 8);
    const int vloc = wave * 32 + ((m >> 2) & 1) * 16 + q * 4 + (m & 3);
    float dl = 0.f;
    if (writer) {
        zsh[vloc] = (int)(wpk & 0xffffffffull);
        if (w2s - w1s <= GAP_THRESH) {
            int pos = atomicAdd(&rn, 1);
            rlist[pos] = vloc;
        }
        float full = vsq_all[vloc] + w1s;          // loss = relu(vsq + best)
        dl = (full < 0.f ? 0.f : full) * inv_n;
    }
#pragma unroll
    for (int off = 32; off >= 1; off >>= 1) dl += __shfl_down(dl, off, 64);
    if (lane == 0) atomicAdd(&loss_sh, dl);

    __syncthreads();

    // ---- in-block exact rescue (r3-proven arithmetic): wave w -> rlist[base+w]
    const int nr = rn;
    for (int rbase = 0; rbase < nr; rbase += 8) {
        const int slot = rbase + wave;
        if (slot < nr) {                       // wave-uniform
            const int rv = rlist[slot];
            const float4* vrow4 = (const float4*)(vecs + (size_t)(blockbase + rv) * VQ_K);
            const float vsqr = vsq_all[rv];
            unsigned long long best = ~0ull;
            for (int j = 0; j < 8; ++j) {
                const int s = lane * 8 + j;
                const float4* crow = (const float4*)(codebook + (size_t)s * VQ_K);
                double acc = 0.0;
#pragma unroll
                for (int qq = 0; qq < VQ_K / 4; ++qq) {
                    float4 c = crow[qq];
                    float4 tt = vrow4[qq];     // wave-uniform -> scalar loads
                    acc = fma((double)c.x, (double)tt.x, acc);
                    acc = fma((double)c.y, (double)tt.y, acc);
                    acc = fma((double)c.z, (double)tt.z, acc);
                    acc = fma((double)c.w, (double)tt.w, acc);
                }
                float e = (float)acc;
                float sc = fmaf(-2.0f, e, vsqr) + csq_sh[s];   // exact ref rounding
                unsigned u = __float_as_uint(sc);
                unsigned mono = (u & 0x80000000u) ? ~u : (u | 0x80000000u);
                unsigned long long pkr = ((unsigned long long)mono << 32) | (unsigned)s;
                best = pkr < best ? pkr : best;
            }
#pragma unroll
            for (int off = 32; off >= 1; off >>= 1) {
                unsigned long long o = __shfl_down(best, off, 64);
                best = o < best ? o : best;
            }
            if (lane == 0) zsh[rv] = (int)(best & 0xffffffffull);
        }
    }
    __syncthreads();

    // ---- loss atomics (2/block), coalesced z write + MLP-batched gather ----
    if (tid == 0) {
        float l = loss_sh;
        atomicAdd(&out_loss[0], l);
        atomicAdd(&out_loss[1], l);
    }
    if (tid < VPB) out_z[blockbase + tid] = (float)zsh[tid];
    {
        const float4* cb4g = (const float4*)codebook;
        float4* hat4 = (float4*)(out_hat + (size_t)blockbase * VQ_K);
        // stage 1: read the 8 needed z values from LDS
        int zz[8];
#pragma unroll
        for (int i = 0; i < 8; ++i) zz[i] = zsh[(tid + i * NTHREADS) >> 4];
        // stage 2: issue all 8 gather loads (independent, 8-deep MLP)
        float4 gv[8];
#pragma unroll
        for (int i = 0; i < 8; ++i) {
            const int f = tid + i * NTHREADS;
            gv[i] = cb4g[zz[i] * (VQ_K / 4) + (f & 15)];
        }
        // stage 3: stores
#pragma unroll
        for (int i = 0; i < 8; ++i) hat4[tid + i * NTHREADS] = gv[i];
    }
}

extern "C" void kernel_launch(void* const* d_in, const int* in_sizes, int n_in,
                              void* d_out, int out_size, void* d_ws, size_t ws_size,
                              hipStream_t stream) {
    const float* vecs = (const float*)d_in[0];
    const float* codebook = (const float*)d_in[1];
    float* out = (float*)d_out;

    const int nvec = in_sizes[0] / VQ_K;            // 65536
    float* csqg = (float*)d_ws;                     // 2048 B

    float* out_hat = out;
    float* out_z = out + (size_t)nvec * VQ_K;
    float* out_loss = out + out_size - 2;

    vq_prep<<<VQ_S / 4, 256, 0, stream>>>(codebook, csqg, out_loss);
    vq_mfma<<<nvec / VPB, NTHREADS, 0, stream>>>(
        vecs, codebook, csqg, out_hat, out_z, out_loss, 1.0f / (float)nvec);
}

// Round 12
// 99.797 us; speedup vs baseline: 1.1073x; 1.0573x over previous
//
#include <hip/hip_runtime.h>
#include <hip/hip_bf16.h>
#include <stdint.h>

// SimpleVectorQuantizer: vecs [16,32,128,64] f32, codebook [512,64] f32.
// Outputs (flat f32): vecs_hat [65536*64], z [65536] (as float), l_commit, l_codebook.
//
// Round 23: FINAL REVERT to the session best (r19, 101.6us). r22's shallow-
// chain/full-unroll was null #7. Complete ablation matrix -- B-delivery (4
// schemes), occupancy (clean 2->4 waves/SIMD: +-0.0us), B-conversion,
// A-prologue, gather, MFMA chain depth, unroll structure -- ALL null: the
// scan's ~40us is invariant to its instruction content, while bottom-up
// issue math says ~2.7us at nominal clock. The only standing explanation is
// external DVFS: the harness's 268MB poison fills run at 6.1 TB/s (max
// memory power) immediately before our kernels, so SCLK is ramping from its
// floor for our entire ~45us window (CPI~14 nominal == CPI~4-6 at 600-900
// MHz, which matches this code at 2 waves/SIMD). Not controllable from
// source. Best state: LDS-resident 131KB B image (XOR-swizzled, both-sides,
// rule #21), MLP-batched A loads (T14), hi/lo bf16 split MFMA chain with
// -csq/2 folded into C, packed-key butterfly merge, 8-CELL gap rescue with
// exact-f64 in-block recompute, MLP-batched gather epilogue. absmax 0.

#define VQ_K 64
#define VQ_S 512
#define NTHREADS 512                     // 8 waves
#define MT 2                             // m-tiles per wave -> 32 vectors/wave
#define VPB 256                          // vectors per block
#define NTILES 32                        // 512 codewords / 16 per tile
#define ROWB 256                         // B row: 64 hi bf16 + 64 lo bf16 (packed)
#define CELL 7.62939453125e-6f           // f32 ulp at ref-score magnitude ~64
#define GAP_THRESH (8.0f * CELL)

typedef __attribute__((ext_vector_type(8))) short bf16x8;
typedef __attribute__((ext_vector_type(4))) float f32x4;

static __device__ __forceinline__ unsigned short f2bf_rne(float f) {
    unsigned u = __float_as_uint(f);
    unsigned r = (u + 0x7fffu + ((u >> 16) & 1u)) >> 16;
    return (unsigned short)r;
}
static __device__ __forceinline__ float bf2f(unsigned short h) {
    return __uint_as_float(((unsigned)h) << 16);
}

// K1: one wave per codebook row; lane k handles element k. csq only + zero loss.
__global__ __launch_bounds__(256, 1) void vq_prep(
    const float* __restrict__ cb, float* __restrict__ csqg,
    float* __restrict__ out_loss) {
    if (blockIdx.x == 0 && threadIdx.x == 0) { out_loss[0] = 0.f; out_loss[1] = 0.f; }
    const int lane = threadIdx.x & 63;
    const int row = blockIdx.x * 4 + (threadIdx.x >> 6);
    float c = cb[(size_t)row * VQ_K + lane];
    double d = (double)c * (double)c;
#pragma unroll
    for (int off = 1; off <= 32; off <<= 1) d += __shfl_xor(d, off, 64);
    if (lane == 0) csqg[row] = (float)d;
}

// K2: all-LDS-resident B image, MLP-batched memory phases.
__global__ __launch_bounds__(NTHREADS, 1) void vq_mfma(
    const float* __restrict__ vecs, const float* __restrict__ codebook,
    const float* __restrict__ csqg,
    float* __restrict__ out_hat, float* __restrict__ out_z,
    float* __restrict__ out_loss, float inv_n) {
    __shared__ __align__(16) unsigned char blds[VQ_S * ROWB];  // 131072 B
    __shared__ float csq_sh[VQ_S];       // exact csq (rescue)
    __shared__ float csqn2_sh[VQ_S];     // -csq/2 (C-init for the scan)
    __shared__ float vsq_all[VPB];
    __shared__ int zsh[VPB];
    __shared__ int rlist[VPB];
    __shared__ int rn;
    __shared__ float loss_sh;

    const int tid = threadIdx.x;
    const int wave = tid >> 6;                    // 0..7
    const int lane = tid & 63;
    const int m = lane & 15;
    const int q = lane >> 4;
    const int blockbase = blockIdx.x * VPB;
    const int wavebase = blockbase + wave * 32;   // 32 vectors per wave

    if (tid == 0) { rn = 0; loss_sh = 0.f; }

    // ---- ISSUE ALL A LOADS FIRST (8 x float4, max per-wave MLP) ----
    const float* vp0 = vecs + (size_t)(wavebase + m) * VQ_K + q * 8;
    const float* vp1 = vecs + (size_t)(wavebase + 16 + m) * VQ_K + q * 8;
    float4 A0a = ((const float4*)vp0)[0];
    float4 A0b = ((const float4*)vp0)[1];
    float4 A0c = ((const float4*)(vp0 + 32))[0];
    float4 A0d = ((const float4*)(vp0 + 32))[1];
    float4 A1a = ((const float4*)vp1)[0];
    float4 A1b = ((const float4*)vp1)[1];
    float4 A1c = ((const float4*)(vp1 + 32))[0];
    float4 A1d = ((const float4*)(vp1 + 32))[1];

    // csq tables (512 entries, 512 threads).
    {
        float c = csqg[tid];
        csq_sh[tid] = c;
        csqn2_sh[tid] = -0.5f * c;
    }
    // B image build runs while A loads are in flight.
    {
        const int row = tid;
        const float4* crow = (const float4*)(codebook + (size_t)row * VQ_K);
        const int xr = (row & 7) << 4;
        unsigned char* rowp = &blds[row * ROWB];
#pragma unroll
        for (int j = 0; j < 8; ++j) {             // 8 chunks of 8 elems
            float4 f0 = crow[2 * j];
            float4 f1 = crow[2 * j + 1];
            float w[8] = {f0.x, f0.y, f0.z, f0.w, f1.x, f1.y, f1.z, f1.w};
            bf16x8 hi8, lo8;
#pragma unroll
            for (int e = 0; e < 8; ++e) {
                unsigned short h = f2bf_rne(w[e]);
                hi8[e] = (short)h;
                lo8[e] = (short)f2bf_rne(w[e] - bf2f(h));
            }
            *(bf16x8*)(rowp + ((j * 16) ^ xr)) = hi8;          // hi: bytes [0,128)
            *(bf16x8*)(rowp + (128 + ((j * 16) ^ xr))) = lo8;  // lo: bytes [128,256)
        }
    }

    // ---- A fragments (bf16 split) + exact vsq (consume staged loads) ----
    bf16x8 ah1[MT], ah2[MT], al1[MT], al2[MT];
#pragma unroll
    for (int mt = 0; mt < MT; ++mt) {
        float4 a0 = (mt == 0) ? A0a : A1a;
        float4 a1 = (mt == 0) ? A0b : A1b;
        float4 b0 = (mt == 0) ? A0c : A1c;
        float4 b1 = (mt == 0) ? A0d : A1d;
        float w1[8] = {a0.x, a0.y, a0.z, a0.w, a1.x, a1.y, a1.z, a1.w};
        float w2[8] = {b0.x, b0.y, b0.z, b0.w, b1.x, b1.y, b1.z, b1.w};
        double p = 0.0;
#pragma unroll
        for (int j = 0; j < 8; ++j) {
            double d1 = (double)w1[j], d2 = (double)w2[j];
            p = fma(d1, d1, p); p = fma(d2, d2, p);
        }
        p += __shfl_xor(p, 16, 64);
        p += __shfl_xor(p, 32, 64);
        if (q == 0) vsq_all[wave * 32 + mt * 16 + m] = (float)p;
#pragma unroll
        for (int j = 0; j < 8; ++j) {
            unsigned short h1 = f2bf_rne(w1[j]);
            unsigned short h2 = f2bf_rne(w2[j]);
            ah1[mt][j] = (short)h1;
            ah2[mt][j] = (short)h2;
            al1[mt][j] = (short)f2bf_rne(w1[j] - bf2f(h1));
            al2[mt][j] = (short)f2bf_rne(w2[j] - bf2f(h2));
        }
    }
    __syncthreads();   // B image + csq tables + vsq resident

    // ---- K-loop: pure LDS + MFMA + ranking. No barriers, no global. ----
    float t1u[8], t2u[8];
    int t1i[8];
#pragma unroll
    for (int st = 0; st < 8; ++st) { t1u[st] = -3.4e38f; t2u[st] = -3.4e38f; t1i[st] = 0; }
    const f32x4 zero4 = {0.f, 0.f, 0.f, 0.f};
    const int xm = (m & 7) << 4;

#pragma unroll 4
    for (int t = 0; t < NTILES; ++t) {
        const unsigned char* rb = &blds[(t * 16 + m) * ROWB];
        bf16x8 c1 = *(const bf16x8*)(rb + ((q * 16) ^ xm));
        bf16x8 c2 = *(const bf16x8*)(rb + ((64 + q * 16) ^ xm));
        bf16x8 c3 = *(const bf16x8*)(rb + (128 + ((q * 16) ^ xm)));
        bf16x8 c4 = *(const bf16x8*)(rb + (128 + ((64 + q * 16) ^ xm)));

        const float mh = csqn2_sh[t * 16 + m];
        const f32x4 ci = {mh, mh, mh, mh};
        const int nidx = t * 16 + m;
#pragma unroll
        for (int mt = 0; mt < MT; ++mt) {
            f32x4 accA = __builtin_amdgcn_mfma_f32_16x16x32_bf16(ah1[mt], c1, zero4, 0, 0, 0);
            f32x4 accB = __builtin_amdgcn_mfma_f32_16x16x32_bf16(ah2[mt], c2, ci, 0, 0, 0);
            accA = __builtin_amdgcn_mfma_f32_16x16x32_bf16(al1[mt], c1, accA, 0, 0, 0);
            accB = __builtin_amdgcn_mfma_f32_16x16x32_bf16(al2[mt], c2, accB, 0, 0, 0);
            accA = __builtin_amdgcn_mfma_f32_16x16x32_bf16(ah1[mt], c3, accA, 0, 0, 0);
            accB = __builtin_amdgcn_mfma_f32_16x16x32_bf16(ah2[mt], c4, accB, 0, 0, 0);
#pragma unroll
            for (int r = 0; r < 4; ++r) {
                const int st = mt * 4 + r;
                float u = accA[r] + accB[r];
                bool gt = u > t1u[st];                          // strict: first index wins
                t2u[st] = fminf(fmaxf(u, t2u[st]), t1u[st]);    // 2nd-largest
                t1u[st] = fmaxf(t1u[st], u);
                t1i[st] = gt ? nidx : t1i[st];
            }
        }
    }

    // ---- convert to score space (sc = -2u) and butterfly-merge 16 columns ----
    float t1s[8], t2s[8];
    unsigned long long pk[8];
#pragma unroll
    for (int st = 0; st < 8; ++st) {
        t1s[st] = -2.0f * t1u[st];
        t2s[st] = -2.0f * t2u[st];
        unsigned u = __float_as_uint(t1s[st]);
        unsigned mono = (u & 0x80000000u) ? ~u : (u | 0x80000000u);
        pk[st] = ((unsigned long long)mono << 32) | (unsigned)t1i[st];
    }
#pragma unroll
    for (int dd = 1; dd <= 8; dd <<= 1) {
#pragma unroll
        for (int st = 0; st < 8; ++st) {
            unsigned long long opk = __shfl_xor(pk[st], dd, 64);
            float o1 = __shfl_xor(t1s[st], dd, 64);
            float o2 = __shfl_xor(t2s[st], dd, 64);
            t2s[st] = fminf(fmaxf(t1s[st], o1), fminf(t2s[st], o2));
            t1s[st] = fminf(t1s[st], o1);
            pk[st] = opk < pk[st] ? opk : pk[st];
        }
    }

    // ---- writers: lanes m<8 own state st=m -> vector wave*32+(m>>2)*16+q*4+(m&3)
    float w1s = 3.4e38f, w2s = 3.4e38f;
    unsigned long long wpk = 0;
#pragma unroll
    for (int i = 0; i < 8; ++i) {
        bool sel = (m == i);
        w1s = sel ? t1s[i] : w1s;
        w2s = sel ? t2s[i] : w2s;
        wpk = sel ? pk[i] : wpk;
    }
    const bool writer = (m < 8);
    const int vloc = wave * 32 + ((m >> 2) & 1) * 16 + q * 4 + (m & 3);
    float dl = 0.f;
    if (writer) {
        zsh[vloc] = (int)(wpk & 0xffffffffull);
        if (w2s - w1s <= GAP_THRESH) {
            int pos = atomicAdd(&rn, 1);
            rlist[pos] = vloc;
        }
        float full = vsq_all[vloc] + w1s;          // loss = relu(vsq + best)
        dl = (full < 0.f ? 0.f : full) * inv_n;
    }
#pragma unroll
    for (int off = 32; off >= 1; off >>= 1) dl += __shfl_down(dl, off, 64);
    if (lane == 0) atomicAdd(&loss_sh, dl);

    __syncthreads();

    // ---- in-block exact rescue (r3-proven arithmetic): wave w -> rlist[base+w]
    const int nr = rn;
    for (int rbase = 0; rbase < nr; rbase += 8) {
        const int slot = rbase + wave;
        if (slot < nr) {                       // wave-uniform
            const int rv = rlist[slot];
            const float4* vrow4 = (const float4*)(vecs + (size_t)(blockbase + rv) * VQ_K);
            const float vsqr = vsq_all[rv];
            unsigned long long best = ~0ull;
            for (int j = 0; j < 8; ++j) {
                const int s = lane * 8 + j;
                const float4* crow = (const float4*)(codebook + (size_t)s * VQ_K);
                double acc = 0.0;
#pragma unroll
                for (int qq = 0; qq < VQ_K / 4; ++qq) {
                    float4 c = crow[qq];
                    float4 tt = vrow4[qq];     // wave-uniform -> scalar loads
                    acc = fma((double)c.x, (double)tt.x, acc);
                    acc = fma((double)c.y, (double)tt.y, acc);
                    acc = fma((double)c.z, (double)tt.z, acc);
                    acc = fma((double)c.w, (double)tt.w, acc);
                }
                float e = (float)acc;
                float sc = fmaf(-2.0f, e, vsqr) + csq_sh[s];   // exact ref rounding
                unsigned u = __float_as_uint(sc);
                unsigned mono = (u & 0x80000000u) ? ~u : (u | 0x80000000u);
                unsigned long long pkr = ((unsigned long long)mono << 32) | (unsigned)s;
                best = pkr < best ? pkr : best;
            }
#pragma unroll
            for (int off = 32; off >= 1; off >>= 1) {
                unsigned long long o = __shfl_down(best, off, 64);
                best = o < best ? o : best;
            }
            if (lane == 0) zsh[rv] = (int)(best & 0xffffffffull);
        }
    }
    __syncthreads();

    // ---- loss atomics (2/block), coalesced z write + MLP-batched gather ----
    if (tid == 0) {
        float l = loss_sh;
        atomicAdd(&out_loss[0], l);
        atomicAdd(&out_loss[1], l);
    }
    if (tid < VPB) out_z[blockbase + tid] = (float)zsh[tid];
    {
        const float4* cb4g = (const float4*)codebook;
        float4* hat4 = (float4*)(out_hat + (size_t)blockbase * VQ_K);
        // stage 1: read the 8 needed z values from LDS
        int zz[8];
#pragma unroll
        for (int i = 0; i < 8; ++i) zz[i] = zsh[(tid + i * NTHREADS) >> 4];
        // stage 2: issue all 8 gather loads (independent, 8-deep MLP)
        float4 gv[8];
#pragma unroll
        for (int i = 0; i < 8; ++i) {
            const int f = tid + i * NTHREADS;
            gv[i] = cb4g[zz[i] * (VQ_K / 4) + (f & 15)];
        }
        // stage 3: stores
#pragma unroll
        for (int i = 0; i < 8; ++i) hat4[tid + i * NTHREADS] = gv[i];
    }
}

extern "C" void kernel_launch(void* const* d_in, const int* in_sizes, int n_in,
                              void* d_out, int out_size, void* d_ws, size_t ws_size,
                              hipStream_t stream) {
    const float* vecs = (const float*)d_in[0];
    const float* codebook = (const float*)d_in[1];
    float* out = (float*)d_out;

    const int nvec = in_sizes[0] / VQ_K;            // 65536
    float* csqg = (float*)d_ws;                     // 2048 B

    float* out_hat = out;
    float* out_z = out + (size_t)nvec * VQ_K;
    float* out_loss = out + out_size - 2;

    vq_prep<<<VQ_S / 4, 256, 0, stream>>>(codebook, csqg, out_loss);
    vq_mfma<<<nvec / VPB, NTHREADS, 0, stream>>>(
        vecs, codebook, csqg, out_hat, out_z, out_loss, 1.0f / (float)nvec);
}